// Round 10
// baseline (277.209 us; speedup 1.0000x reference)
//
#include <hip/hip_runtime.h>
#include <hip/hip_bf16.h>
#include <math.h>

// ---------------------------------------------------------------------------
// PSI_47931835024047: x@W_omega -> chunked phase cumsum/rotation -> LN ->
//                     W1+gelu -> W2 + residual.
// B=4 S=4096 D=512 C=64. All GEMMs bf16 MFMA.
// R19: SCAN FUSED INTO GEMM2. Decomposition from R15/R17/R18: the
//      barrier-per-token scan costs ~115 us; the R17 wave-local scan is
//      ~5-10 us but standalone it idles the machine (256 waves) -> DVFS
//      clock drop poisons everything (R17: uniform ~2.06x dilation).
//      Fix: each gemm2 block scans its OWN 4 chunks (waves 0-3, 1 wave per
//      chunk, 8 d/lane, zero barriers) before its GEMM. 1024 active waves
//      during the scan phase (R18-proven safe), no idle window, no
//      standalone launch. The 4 n-blocks per m-tile scan redundantly --
//      identical values, benign write race; each block reads only its own
//      drained writes (vmcnt(0) + __syncthreads, same-XCD L2).
// ---------------------------------------------------------------------------

typedef __bf16 bf16x8 __attribute__((ext_vector_type(8)));
typedef __bf16 bf16x4 __attribute__((ext_vector_type(4)));
typedef __bf16 bf16x2 __attribute__((ext_vector_type(2)));
typedef float  f32x4  __attribute__((ext_vector_type(4)));

typedef __attribute__((address_space(1))) void* gas_ptr;
typedef __attribute__((address_space(3))) void* las_ptr;

// wave-uniform LDS base; each lane deposits 16 B at base + lane*16
__device__ __forceinline__ void load_lds16(const void* g, void* l) {
    __builtin_amdgcn_global_load_lds((gas_ptr)g, (las_ptr)l, 16, 0, 0);
}

// ---------------------------------------------------------------------------
// Fused prep: block ranges do (a) x->bf16 cast, (b) W_omega^T, (c) W1^T,
// (d) W2^T. One launch instead of four.
// ---------------------------------------------------------------------------
__device__ __forceinline__ void transpose_tile(const float* __restrict__ in,
                                               __bf16* __restrict__ out,
                                               int K, int N, int bx, int by,
                                               float (*tile)[33])
{
    const int tid = threadIdx.x;
    const int tx = tid & 31, ty = tid >> 5;       // (32, 8)
    const int n0 = bx * 32, k0 = by * 32;
    #pragma unroll
    for (int i = 0; i < 32; i += 8)
        tile[ty + i][tx] = in[(size_t)(k0 + ty + i) * N + n0 + tx];
    __syncthreads();
    #pragma unroll
    for (int i = 0; i < 32; i += 8)
        out[(size_t)(n0 + ty + i) * K + k0 + tx] = (__bf16)tile[tx][ty + i];
}

__global__ __launch_bounds__(256)
void prep_kernel(const float* __restrict__ x, __bf16* __restrict__ xb,
                 const float* __restrict__ W_omega, __bf16* __restrict__ womT,
                 const float* __restrict__ W1, __bf16* __restrict__ w1T,
                 const float* __restrict__ W2, __bf16* __restrict__ w2T)
{
    __shared__ float tile[32][33];
    const int bid = blockIdx.x;
    if (bid < 8192) {
        int i = bid * 256 + threadIdx.x;          // 2097152 float4's
        float4 v = ((const float4*)x)[i];
        bf16x4 o = { (__bf16)v.x, (__bf16)v.y, (__bf16)v.z, (__bf16)v.w };
        ((bf16x4*)xb)[i] = o;
    } else if (bid < 8448) {
        int t = bid - 8192;                       // 16 x 16
        transpose_tile(W_omega, womT, 512, 512, t & 15, t >> 4, tile);
    } else if (bid < 10496) {
        int t = bid - 8448;                       // 32 x 64
        transpose_tile(W1, w1T, 2048, 1024, t & 31, t >> 5, tile);
    } else {
        int t = bid - 10496;                      // 16 x 32
        transpose_tile(W2, w2T, 1024, 512, t & 15, t >> 4, tile);
    }
}

// ---------------------------------------------------------------------------
// bf16 MFMA GEMM (R7 structure): 128x128 tile, 4 waves, BK=64 double-buffered.
// Used for GEMM1 (MODE 0) and GEMM3 (MODE 2).
// ---------------------------------------------------------------------------
template<int MODE>
__global__ __launch_bounds__(256)
void gemm_kernel(const __bf16* __restrict__ A, const __bf16* __restrict__ Bt,
                 const float* __restrict__ bias, const __bf16* __restrict__ resid,
                 void* __restrict__ out, int M, int N, int K)
{
    __shared__ __bf16 As[2][128 * 64];
    __shared__ __bf16 Bs[2][128 * 64];

    const int tid     = threadIdx.x;
    const int tiles_n = N >> 7;                 // 4 or 8 (power of 2)
    const int ln_tn   = __ffs(tiles_n) - 1;
    const int per_m   = (M >> 7) >> 3;          // 128-row tiles per XCD

    const int xcd = blockIdx.x & 7;
    const int j   = blockIdx.x >> 3;
    const int tile_m = (xcd * per_m + (j >> ln_tn)) << 7;
    const int tile_n = (j & (tiles_n - 1)) << 7;

    const int wave = tid >> 6;
    const int lane = tid & 63;

    // staging map: lane l -> row (l>>3), chunk (l&7)^((l>>3)&7)
    const int srow = lane >> 3;                       // 0..7
    const int scol = ((lane & 7) ^ srow) << 3;        // elem offset in row

    const __bf16* Ags = A  + (size_t)(tile_m + wave * 32 + srow) * K + scol;
    const __bf16* Bgs = Bt + (size_t)(tile_n + wave * 32 + srow) * K + scol;

    const int m0 = (wave >> 1) << 6;
    const int n0 = (wave & 1) << 6;
    const int lr = lane & 15;
    const int q  = lane >> 4;
    const int l7 = lane & 7;
    const int fc0 = ((0 + q) ^ l7) << 3;   // swizzled elem offset, k-half 0
    const int fc1 = ((4 + q) ^ l7) << 3;   // swizzled elem offset, k-half 1

    f32x4 acc[4][4];
    #pragma unroll
    for (int i = 0; i < 4; ++i)
        #pragma unroll
        for (int jj = 0; jj < 4; ++jj)
            acc[i][jj] = (f32x4){0.f, 0.f, 0.f, 0.f};

    const int nIter = K >> 6;

    // prologue: stage tile 0 into buffer 0
    #pragma unroll
    for (int c = 0; c < 4; ++c) {
        load_lds16(Ags + (size_t)(c * 8) * K, &As[0][(wave * 32 + c * 8) * 64]);
        load_lds16(Bgs + (size_t)(c * 8) * K, &Bs[0][(wave * 32 + c * 8) * 64]);
    }

    for (int it = 0; it < nIter; ++it) {
        const int cur = it & 1;
        __syncthreads();   // drains prefetch issued last iter (aged thru MFMA)
        if (it + 1 < nIter) {
            const int nk = (it + 1) << 6;
            #pragma unroll
            for (int c = 0; c < 4; ++c) {
                load_lds16(Ags + nk + (size_t)(c * 8) * K, &As[cur ^ 1][(wave * 32 + c * 8) * 64]);
                load_lds16(Bgs + nk + (size_t)(c * 8) * K, &Bs[cur ^ 1][(wave * 32 + c * 8) * 64]);
            }
        }

        const __bf16* as = As[cur];
        const __bf16* bs = Bs[cur];
        // k-half 0
        {
            bf16x8 af[4], bq[4];
            #pragma unroll
            for (int i = 0; i < 4; ++i)
                af[i] = *(const bf16x8*)&as[(m0 + i * 16 + lr) * 64 + fc0];
            #pragma unroll
            for (int jj = 0; jj < 4; ++jj)
                bq[jj] = *(const bf16x8*)&bs[(n0 + jj * 16 + lr) * 64 + fc0];
            #pragma unroll
            for (int i = 0; i < 4; ++i)
                #pragma unroll
                for (int jj = 0; jj < 4; ++jj)
                    acc[i][jj] = __builtin_amdgcn_mfma_f32_16x16x32_bf16(af[i], bq[jj], acc[i][jj], 0, 0, 0);
        }
        // k-half 1
        {
            bf16x8 af[4], bq[4];
            #pragma unroll
            for (int i = 0; i < 4; ++i)
                af[i] = *(const bf16x8*)&as[(m0 + i * 16 + lr) * 64 + fc1];
            #pragma unroll
            for (int jj = 0; jj < 4; ++jj)
                bq[jj] = *(const bf16x8*)&bs[(n0 + jj * 16 + lr) * 64 + fc1];
            #pragma unroll
            for (int i = 0; i < 4; ++i)
                #pragma unroll
                for (int jj = 0; jj < 4; ++jj)
                    acc[i][jj] = __builtin_amdgcn_mfma_f32_16x16x32_bf16(af[i], bq[jj], acc[i][jj], 0, 0, 0);
        }
    }

    // epilogue — C/D layout: col = lane&15, row = (lane>>4)*4 + reg  [m89/m91]
    const int orow0 = tile_m + m0 + (q << 2);
    const int ocol0 = tile_n + n0 + lr;
    #pragma unroll
    for (int i = 0; i < 4; ++i) {
        #pragma unroll
        for (int jj = 0; jj < 4; ++jj) {
            const int col = ocol0 + jj * 16;
            const float bv = bias[col];
            #pragma unroll
            for (int r = 0; r < 4; ++r) {
                const int row = orow0 + i * 16 + r;
                float v = acc[i][jj][r] + bv;
                size_t idx = (size_t)row * N + col;
                if (MODE == 0) {
                    ((__bf16*)out)[idx] = (__bf16)v;
                } else if (MODE == 1) {
                    float g = 0.5f * v * (1.0f + erff(v * 0.70710678118654752f));
                    ((__bf16*)out)[idx] = (__bf16)g;
                } else {
                    ((float*)out)[idx] = v + (float)resid[idx];
                }
            }
        }
    }
}

// ---------------------------------------------------------------------------
// R19: fused scan + 256x256 GEMM2 (gelu epilogue).
//
// Phase A (scan, waves 0-3): wave wv scans chunk (tile_m>>6)+wv -- the exact
// 4 chunks whose ctx rows this block's A-tile needs. R17's verified math:
// 8 d/lane, bf16x8 loads/stores, LN reduce = in-lane adds + 6-level
// shfl_xor butterfly, zero barriers, zero LDS. 1024 active waves machine-
// wide (R18-proven safe against the DVFS idle-window poisoning).
// The 4 n-blocks of each m-tile scan redundantly: identical inputs ->
// identical bf16 values -> benign write race on ctx.
// Phase boundary: vmcnt(0) drains this block's ctx stores; __syncthreads
// publishes them block-wide. Reads hit the block's own XCD L2 (hot).
//
// Phase B: R13 GEMM body verbatim (4-slot k-slice ring, 2-deep register
// fragment pipeline, asm ds_read, fine interleave, vmcnt(8) counted waits,
// tail countdown 8/4/0). A = ctx (not restrict: written in phase A).
// ---------------------------------------------------------------------------
__global__ __launch_bounds__(512, 1)
void scan_gemm_kernel(const __bf16* __restrict__ xbp, const __bf16* __restrict__ omega,
                      const float* __restrict__ log_scale,
                      const float* __restrict__ gamma, const float* __restrict__ beta,
                      __bf16* ctx,
                      const __bf16* __restrict__ Bt, const float* __restrict__ bias,
                      __bf16* __restrict__ out, int M, int N, int K)
{
    __shared__ __bf16 As[4][256 * 32];
    __shared__ __bf16 Bs[4][256 * 32];

    const int tid  = threadIdx.x;
    const int wv   = tid >> 6;            // 0..7
    const int lane = tid & 63;
    const int wm   = wv >> 2;             // 0..1  (M half)
    const int wn   = wv & 3;              // 0..3  (N quarter)

    const int tiles_n = N >> 8;                    // 4 (power of 2)
    const int ln_tn   = __ffs(tiles_n) - 1;
    const int per_m   = (M >> 8) >> 3;             // 256-row tiles per XCD

    const int xcd = blockIdx.x & 7;
    const int j   = blockIdx.x >> 3;
    const int tile_m = (xcd * per_m + (j >> ln_tn)) << 8;
    const int tile_n = (j & (tiles_n - 1)) << 8;

    // ================= Phase A: scan 4 chunks (waves 0-3) =================
    if (wv < 4) {
        const int chunk = (tile_m >> 6) + wv;     // 4 chunks per 256-row tile
        const int d0    = lane << 3;              // 8 consecutive d per lane
        const size_t sbase = (size_t)chunk * 64 * 512;

        float scale[8], g0[8], g1[8], g2[8], g3[8], e0[8], e1[8], e2[8], e3[8];
        #pragma unroll
        for (int u = 0; u < 8; ++u) {
            const int d = d0 + u;
            scale[u] = expf(log_scale[d]);
            g0[u] = gamma[d]; g1[u] = gamma[512 + d]; g2[u] = gamma[1024 + d]; g3[u] = gamma[1536 + d];
            e0[u] = beta[d];  e1[u] = beta[512 + d];  e2[u] = beta[1024 + d];  e3[u] = beta[1536 + d];
        }
        float phi[8], scr[8], sci[8];
        #pragma unroll
        for (int u = 0; u < 8; ++u) { phi[u] = 0.f; scr[u] = 0.f; sci[u] = 0.f; }

        bf16x8 om_n = *(const bf16x8*)&omega[sbase + d0];
        bf16x8 xv_n = *(const bf16x8*)&xbp[sbase + d0];

        for (int c = 0; c < 64; ++c) {
            const bf16x8 omv = om_n;
            const bf16x8 xvv = xv_n;
            if (c < 63) {
                om_n = *(const bf16x8*)&omega[sbase + (size_t)(c + 1) * 512 + d0];
                xv_n = *(const bf16x8*)&xbp[sbase + (size_t)(c + 1) * 512 + d0];
            }
            const float rsq = rsqrtf((float)(c + 1));
            const float inv = 1.0f / (float)(c + 1);

            float cr[8], ci[8], rr[8], ri[8];
            float s = 0.f, s2 = 0.f;
            #pragma unroll
            for (int u = 0; u < 8; ++u) {
                const float om = (float)omv[u];
                const float xv = (float)xvv[u];
                phi[u] += om * scale[u] * rsq;
                float sp, cp;
                __sincosf(phi[u], &sp, &cp);
                cr[u] = xv * cp; ci[u] = xv * sp;
                scr[u] += cr[u]; sci[u] += ci[u];
                const float mr = scr[u] * inv, mi = sci[u] * inv;
                rr[u] = mr * cp + mi * sp;
                ri[u] = mi * cp - mr * sp;
                s  += cr[u] + ci[u] + rr[u] + ri[u];
                s2 += cr[u]*cr[u] + ci[u]*ci[u] + rr[u]*rr[u] + ri[u]*ri[u];
            }
            #pragma unroll
            for (int o = 32; o > 0; o >>= 1) {
                s  += __shfl_xor(s, o);
                s2 += __shfl_xor(s2, o);
            }
            const float mu   = s * (1.0f / 2048.0f);
            const float var  = s2 * (1.0f / 2048.0f) - mu * mu;
            const float rstd = rsqrtf(var + 1e-5f);

            const size_t ob = ((size_t)chunk * 64 + c) * 2048;
            bf16x8 o0, o1, o2, o3;
            #pragma unroll
            for (int u = 0; u < 8; ++u) {
                o0[u] = (__bf16)(((cr[u] - mu) * rstd) * g0[u] + e0[u]);
                o1[u] = (__bf16)(((ci[u] - mu) * rstd) * g1[u] + e1[u]);
                o2[u] = (__bf16)(((rr[u] - mu) * rstd) * g2[u] + e2[u]);
                o3[u] = (__bf16)(((ri[u] - mu) * rstd) * g3[u] + e3[u]);
            }
            *(bf16x8*)&ctx[ob + d0]        = o0;
            *(bf16x8*)&ctx[ob + 512 + d0]  = o1;
            *(bf16x8*)&ctx[ob + 1024 + d0] = o2;
            *(bf16x8*)&ctx[ob + 1536 + d0] = o3;
        }
    }
    // drain scan stores (vmcnt counts stores too), publish block-wide
    asm volatile("s_waitcnt vmcnt(0)" ::: "memory");
    __syncthreads();

    // ================= Phase B: R13 GEMM body (A = ctx) =================
    const __bf16* A = ctx;

    // --- staging constants ---------------------------------------------
    const int srow = 16 * wv + (lane >> 2);                       // 0..127
    const int sig8 = (((lane & 3) ^ ((lane >> 3) & 3)) << 3);     // elem off

    const __bf16* Ag = A  + (size_t)(tile_m + srow) * K + sig8;
    const __bf16* Bg = Bt + (size_t)(tile_n + srow) * K + sig8;
    const size_t rowK128 = (size_t)128 * K;
    const int lbase = wv * 512;            // wave-uniform LDS elem base

    // --- fragment-read constants ---------------------------------------
    const int lr    = lane & 15;           // row within 16-row fragment
    const int q4    = lane >> 4;           // logical 16B k-slot 0..3
    const int fslot = ((q4 ^ ((lane >> 1) & 3)) << 3);   // swizzled elem off
    const int arow0 = wm * 128 + lr;
    const int brow0 = wn * 64 + lr;

    // raw 32-bit LDS byte addresses of slot-0 fragments
    const unsigned ldsA0 = (unsigned)(size_t)(las_ptr)&As[0][0];
    const unsigned ldsB0 = (unsigned)(size_t)(las_ptr)&Bs[0][0];
    const unsigned asA = ldsA0 + (unsigned)((arow0 * 32 + fslot) << 1);
    const unsigned asB = ldsB0 + (unsigned)((brow0 * 32 + fslot) << 1);

    f32x4 acc[8][4];
    #pragma unroll
    for (int i = 0; i < 8; ++i)
        #pragma unroll
        for (int jj = 0; jj < 4; ++jj)
            acc[i][jj] = (f32x4){0.f, 0.f, 0.f, 0.f};

    const int NKS = K >> 5;                // k-slices of 32 (even, >= 8)

    auto stage = [&](int ks) {
        const int slot = ks & 3;
        const __bf16* ag = Ag + (ks << 5);
        const __bf16* bg = Bg + (ks << 5);
        load_lds16(ag,           &As[slot][lbase]);
        load_lds16(ag + rowK128, &As[slot][4096 + lbase]);
        load_lds16(bg,           &Bs[slot][lbase]);
        load_lds16(bg + rowK128, &Bs[slot][4096 + lbase]);
    };

    bf16x8 afA[8], bqA[4], afB[8], bqB[4];

#define DSR(d, a, o) asm volatile("ds_read_b128 %0, %1 offset:" o \
                                  : "=v"(d) : "v"(a))
#define SB __builtin_amdgcn_sched_barrier(0)
#define MM4(CAF, CBQ, I)                                                      \
    acc[I][0] = __builtin_amdgcn_mfma_f32_16x16x32_bf16(CAF[I], CBQ[0], acc[I][0], 0, 0, 0); \
    acc[I][1] = __builtin_amdgcn_mfma_f32_16x16x32_bf16(CAF[I], CBQ[1], acc[I][1], 0, 0, 0); \
    acc[I][2] = __builtin_amdgcn_mfma_f32_16x16x32_bf16(CAF[I], CBQ[2], acc[I][2], 0, 0, 0); \
    acc[I][3] = __builtin_amdgcn_mfma_f32_16x16x32_bf16(CAF[I], CBQ[3], acc[I][3], 0, 0, 0);

#define G256_READ(KS, NAF, NBQ)                                               \
    {                                                                         \
        const unsigned aA_ = asA + (unsigned)(((KS) & 3) << 14);              \
        const unsigned aB_ = asB + (unsigned)(((KS) & 3) << 14);              \
        DSR(NAF[0], aA_, "0");    DSR(NAF[1], aA_, "1024");                   \
        DSR(NAF[2], aA_, "2048"); DSR(NAF[3], aA_, "3072");                   \
        DSR(NAF[4], aA_, "4096"); DSR(NAF[5], aA_, "5120");                   \
        DSR(NAF[6], aA_, "6144"); DSR(NAF[7], aA_, "7168");                   \
        DSR(NBQ[0], aB_, "0");    DSR(NBQ[1], aB_, "1024");                   \
        DSR(NBQ[2], aB_, "2048"); DSR(NBQ[3], aB_, "3072");                   \
    }

// steady-state phase: requires ks+4 < NKS (stage valid) and NKS-1-ks >= 3
#define G256_PHASE_FULL(KS, CAF, CBQ, NAF, NBQ)                               \
    {                                                                         \
        const int ks_ = (KS);                                                 \
        asm volatile("s_waitcnt vmcnt(8)" ::: "memory");                      \
        __builtin_amdgcn_s_barrier();                                         \
        asm volatile("" ::: "memory");                                        \
        const int slot_ = (ks_ + 4) & 3;                                      \
        const __bf16* ag_ = Ag + ((ks_ + 4) << 5);                            \
        const __bf16* bg_ = Bg + ((ks_ + 4) << 5);                            \
        const unsigned aA_ = asA + (unsigned)(((ks_ + 1) & 3) << 14);         \
        const unsigned aB_ = asB + (unsigned)(((ks_ + 1) & 3) << 14);         \
        __builtin_amdgcn_s_setprio(1);                                        \
        load_lds16(ag_,           &As[slot_][lbase]);                         \
        MM4(CAF, CBQ, 0) SB;                                                  \
        load_lds16(ag_ + rowK128, &As[slot_][4096 + lbase]);                  \
        MM4(CAF, CBQ, 1) SB;                                                  \
        load_lds16(bg_,           &Bs[slot_][lbase]);                         \
        MM4(CAF, CBQ, 2) SB;                                                  \
        load_lds16(bg_ + rowK128, &Bs[slot_][4096 + lbase]);                  \
        MM4(CAF, CBQ, 3) SB;                                                  \
        DSR(NAF[0], aA_, "0"); DSR(NAF[1], aA_, "1024");                      \
        DSR(NAF[2], aA_, "2048");                                             \
        MM4(CAF, CBQ, 4) SB;                                                  \
        DSR(NAF[3], aA_, "3072"); DSR(NAF[4], aA_, "4096");                   \
        DSR(NAF[5], aA_, "5120");                                             \
        MM4(CAF, CBQ, 5) SB;                                                  \
        DSR(NAF[6], aA_, "6144"); DSR(NAF[7], aA_, "7168");                   \
        DSR(NBQ[0], aB_, "0");                                                \
        MM4(CAF, CBQ, 6) SB;                                                  \
        DSR(NBQ[1], aB_, "1024"); DSR(NBQ[2], aB_, "2048");                   \
        DSR(NBQ[3], aB_, "3072");                                             \
        MM4(CAF, CBQ, 7)                                                      \
        __builtin_amdgcn_s_setprio(0);                                        \
        asm volatile("s_waitcnt lgkmcnt(0)" ::: "memory");                    \
        __builtin_amdgcn_sched_barrier(0);                                    \
    }

// tail phase: guarded stages/reads, vmcnt countdown 8/4/0
#define G256_PHASE_TAIL(KS, CAF, CBQ, NAF, NBQ)                               \
    {                                                                         \
        const int ks_ = (KS);                                                 \
        const int r_  = NKS - 1 - ks_;                                        \
        if (r_ >= 3)      asm volatile("s_waitcnt vmcnt(8)" ::: "memory");    \
        else if (r_ == 2) asm volatile("s_waitcnt vmcnt(4)" ::: "memory");    \
        else if (r_ == 1) asm volatile("s_waitcnt vmcnt(0)" ::: "memory");    \
        __builtin_amdgcn_s_barrier();                                         \
        asm volatile("" ::: "memory");                                        \
        if (ks_ + 4 < NKS) stage(ks_ + 4);                                    \
        if (ks_ + 1 < NKS) G256_READ(ks_ + 1, NAF, NBQ)                       \
        __builtin_amdgcn_s_setprio(1);                                        \
        _Pragma("unroll")                                                     \
        for (int i_ = 0; i_ < 8; ++i_)                                        \
            _Pragma("unroll")                                                 \
            for (int j_ = 0; j_ < 4; ++j_)                                    \
                acc[i_][j_] = __builtin_amdgcn_mfma_f32_16x16x32_bf16(        \
                    CAF[i_], CBQ[j_], acc[i_][j_], 0, 0, 0);                  \
        __builtin_amdgcn_s_setprio(0);                                        \
        asm volatile("s_waitcnt lgkmcnt(0)" ::: "memory");                    \
        __builtin_amdgcn_sched_barrier(0);                                    \
    }

    // prologue: slices 0..2 in flight, then certify slice 0 and preload its
    // fragments into set A (the ks=0 phase's "current" set).
    stage(0); stage(1); stage(2);
    asm volatile("s_waitcnt vmcnt(8)" ::: "memory");   // stage(0) retired
    __builtin_amdgcn_s_barrier();                      // slice 0 published
    asm volatile("" ::: "memory");
    stage(3);                                          // slot 3 (no conflict)
    G256_READ(0, afA, bqA)
    asm volatile("s_waitcnt lgkmcnt(0)" ::: "memory"); // drained before ks=0 barrier
    __builtin_amdgcn_sched_barrier(0);

    int ks = 0;
    for (; ks + 6 < NKS; ks += 2) {
        G256_PHASE_FULL(ks,     afA, bqA, afB, bqB)
        G256_PHASE_FULL(ks + 1, afB, bqB, afA, bqA)
    }
    for (; ks < NKS; ks += 2) {
        G256_PHASE_TAIL(ks,     afA, bqA, afB, bqB)
        G256_PHASE_TAIL(ks + 1, afB, bqB, afA, bqA)
    }

#undef G256_PHASE_FULL
#undef G256_PHASE_TAIL
#undef G256_READ
#undef MM4
#undef SB
#undef DSR

    // epilogue — gelu, bf16 store. C/D layout: col = lane&15, row = q*4+reg
    const int orow0 = tile_m + wm * 128 + (q4 << 2);
    const int ocol0 = tile_n + wn * 64 + lr;
    #pragma unroll
    for (int i = 0; i < 8; ++i) {
        #pragma unroll
        for (int jj = 0; jj < 4; ++jj) {
            const int col = ocol0 + jj * 16;
            const float bv = bias[col];
            #pragma unroll
            for (int r = 0; r < 4; ++r) {
                const int row = orow0 + i * 16 + r;
                float v = acc[i][jj][r] + bv;
                float g = 0.5f * v * (1.0f + erff(v * 0.70710678118654752f));
                out[(size_t)row * N + col] = (__bf16)g;
            }
        }
    }
}

// ---------------------------------------------------------------------------
// Workspace layout (bytes):
//   xb    @ 0          : 16,777,216  (16384x512 bf16)
//   womT  @ 16777216   : 524,288     (512x512 bf16, transposed)
//   w1T   @ 17301504   : 4,194,304   (1024x2048 bf16, transposed)
//   w2T   @ 21495808   : 1,048,576   (512x1024 bf16, transposed)
//   omega @ 22544384   : 16,777,216  (16384x512 bf16) — region reused as h
//   h     @ 22544384   : 33,554,432  (16384x1024 bf16)
//   ctx   @ 56098816   : 67,108,864  (16384x2048 bf16)
// ---------------------------------------------------------------------------
extern "C" void kernel_launch(void* const* d_in, const int* in_sizes, int n_in,
                              void* d_out, int out_size, void* d_ws, size_t ws_size,
                              hipStream_t stream)
{
    const float* x         = (const float*)d_in[0];
    const float* W_omega   = (const float*)d_in[1];
    const float* b_omega   = (const float*)d_in[2];
    const float* log_scale = (const float*)d_in[3];
    const float* ln_gamma  = (const float*)d_in[4];
    const float* ln_beta   = (const float*)d_in[5];
    const float* W1        = (const float*)d_in[6];
    const float* b1        = (const float*)d_in[7];
    const float* W2        = (const float*)d_in[8];
    const float* b2        = (const float*)d_in[9];
    float* out = (float*)d_out;

    char* ws = (char*)d_ws;
    __bf16* xb    = (__bf16*)(ws);
    __bf16* womT  = (__bf16*)(ws + 16777216);
    __bf16* w1T   = (__bf16*)(ws + 17301504);
    __bf16* w2T   = (__bf16*)(ws + 21495808);
    __bf16* omega = (__bf16*)(ws + 22544384);
    __bf16* hbuf  = (__bf16*)(ws + 22544384);   // reuses omega region
    __bf16* ctx   = (__bf16*)(ws + 56098816);

    // 1. fused cast + weight transposes (one launch)
    prep_kernel<<<11008, 256, 0, stream>>>(x, xb, W_omega, womT, W1, w1T, W2, w2T);

    // 2. omega = x @ W_omega + b_omega   (bf16 out)
    gemm_kernel<0><<<512, 256, 0, stream>>>(xb, womT, b_omega, nullptr, omega, 16384, 512, 512);

    // 3+4. fused: per-block scan of its 4 chunks -> ctx, then
    //      h = gelu(ctx @ W1 + b1). hbuf reuses the omega region -- safe:
    //      each block reads omega (scan phase) strictly before any h-write
    //      could touch those rows? NO -- different blocks overlap. hbuf and
    //      omega alias! Writes to hbuf by an early block could corrupt
    //      omega rows another block's scan still needs. Use a separate h
    //      region instead (ctx + 67108864 fits? ws has room: h placed after
    //      ctx at offset 123207680).
    {
        __bf16* hsafe = (__bf16*)(ws + 123207680);   // 33,554,432 bytes
        scan_gemm_kernel<<<256, 512, 0, stream>>>(xb, omega, log_scale, ln_gamma,
                                                  ln_beta, ctx, w1T, b1, hsafe,
                                                  16384, 1024, 2048);

        // 5. out = x + h @ W2 + b2    (fp32 out, bf16 residual)
        gemm_kernel<2><<<512, 256, 0, stream>>>(hsafe, w2T, b2, xb, out, 16384, 512, 1024);
    }
}

// Round 11
// 258.786 us; speedup vs baseline: 1.0712x; 1.0712x over previous
//
#include <hip/hip_runtime.h>
#include <hip/hip_bf16.h>
#include <math.h>

// ---------------------------------------------------------------------------
// PSI_47931835024047: x@W_omega -> chunked phase cumsum/rotation -> LN ->
//                     W1+gelu -> W2 + residual.
// B=4 S=4096 D=512 C=64. All GEMMs bf16 MFMA.
// R20: R19 fusion killed (scan-in-kernel cost 65us vs 52 standalone: 4x
//      redundant traffic + 1-wave/SIMD latencies; net -13us). Closed
//      accounting: gemm256 81.5 + scan 52 + prep/gemm1/gemm3 130. New
//      target: gemm1+gemm3 move from the 128^2 2-barrier kernel (weak at
//      N=512 shapes) to a 256x128-tile R13-ring variant: 8 waves 4Mx2N,
//      64x64/wave, 3 loads/slice (vmcnt 6/3/0), LDS 96KB, grid 256 =
//      1 block/CU. Swizzle/accumulation order carried over unchanged.
// ---------------------------------------------------------------------------

typedef __bf16 bf16x8 __attribute__((ext_vector_type(8)));
typedef __bf16 bf16x4 __attribute__((ext_vector_type(4)));
typedef __bf16 bf16x2 __attribute__((ext_vector_type(2)));
typedef float  f32x4  __attribute__((ext_vector_type(4)));

typedef __attribute__((address_space(1))) void* gas_ptr;
typedef __attribute__((address_space(3))) void* las_ptr;

// wave-uniform LDS base; each lane deposits 16 B at base + lane*16
__device__ __forceinline__ void load_lds16(const void* g, void* l) {
    __builtin_amdgcn_global_load_lds((gas_ptr)g, (las_ptr)l, 16, 0, 0);
}

// ---------------------------------------------------------------------------
// Fused prep: block ranges do (a) x->bf16 cast, (b) W_omega^T, (c) W1^T,
// (d) W2^T. One launch instead of four.
// ---------------------------------------------------------------------------
__device__ __forceinline__ void transpose_tile(const float* __restrict__ in,
                                               __bf16* __restrict__ out,
                                               int K, int N, int bx, int by,
                                               float (*tile)[33])
{
    const int tid = threadIdx.x;
    const int tx = tid & 31, ty = tid >> 5;       // (32, 8)
    const int n0 = bx * 32, k0 = by * 32;
    #pragma unroll
    for (int i = 0; i < 32; i += 8)
        tile[ty + i][tx] = in[(size_t)(k0 + ty + i) * N + n0 + tx];
    __syncthreads();
    #pragma unroll
    for (int i = 0; i < 32; i += 8)
        out[(size_t)(n0 + ty + i) * K + k0 + tx] = (__bf16)tile[tx][ty + i];
}

__global__ __launch_bounds__(256)
void prep_kernel(const float* __restrict__ x, __bf16* __restrict__ xb,
                 const float* __restrict__ W_omega, __bf16* __restrict__ womT,
                 const float* __restrict__ W1, __bf16* __restrict__ w1T,
                 const float* __restrict__ W2, __bf16* __restrict__ w2T)
{
    __shared__ float tile[32][33];
    const int bid = blockIdx.x;
    if (bid < 8192) {
        int i = bid * 256 + threadIdx.x;          // 2097152 float4's
        float4 v = ((const float4*)x)[i];
        bf16x4 o = { (__bf16)v.x, (__bf16)v.y, (__bf16)v.z, (__bf16)v.w };
        ((bf16x4*)xb)[i] = o;
    } else if (bid < 8448) {
        int t = bid - 8192;                       // 16 x 16
        transpose_tile(W_omega, womT, 512, 512, t & 15, t >> 4, tile);
    } else if (bid < 10496) {
        int t = bid - 8448;                       // 32 x 64
        transpose_tile(W1, w1T, 2048, 1024, t & 31, t >> 5, tile);
    } else {
        int t = bid - 10496;                      // 16 x 32
        transpose_tile(W2, w2T, 1024, 512, t & 15, t >> 4, tile);
    }
}

// ---------------------------------------------------------------------------
// R20: 256x128-tile GEMM (R13 ring structure) for GEMM1 (MODE 0) and GEMM3
// (MODE 2). 512 threads = 8 waves as 4M x 2N (64x64 output each, acc[4][4]).
//
// LDS: As[4][256*32] (16KB/slot) + Bs[4][128*32] (8KB/slot) = 96 KiB.
// Per k-slice stage = 3 x global_load_lds (A rows 0-127, A rows 128-255,
// B rows 0-127); ring depth 3 -> vmcnt(6) steady, countdown 6/3/0 in tail.
// Staging swizzle sigma = (lane&3)^((lane>>3)&3) (rows = 16wv + lane>>2,
// row-offset multiples of 128 preserve (row>>1)&3). Read fslot =
// (q4 ^ ((lane>>1)&3)) -- valid since wm*64, wn*64 are 0 mod 8.
// Per-phase interleave: 4 groups of {1-2 LDS/global ops; 4 MFMA},
// sched_barrier-pinned, setprio around MFMA. Accumulation k-order identical
// to the 128^2 kernel (k-slices in order) -> same numerics.
// Grid = (M/256)*(N/128); requires NKS = K/32 even >= 8 (K=512/1024 ok).
//   MODE 0: +bias, store bf16.   MODE 2: +bias +bf16 resid, store fp32.
// ---------------------------------------------------------------------------
template<int MODE>
__global__ __launch_bounds__(512, 1)
void gemm128_kernel(const __bf16* __restrict__ A, const __bf16* __restrict__ Bt,
                    const float* __restrict__ bias, const __bf16* __restrict__ resid,
                    void* __restrict__ out, int M, int N, int K)
{
    __shared__ __bf16 As[4][256 * 32];
    __shared__ __bf16 Bs[4][128 * 32];

    const int tid  = threadIdx.x;
    const int wv   = tid >> 6;            // 0..7
    const int lane = tid & 63;
    const int wm   = wv >> 1;             // 0..3  (M quarter, 64 rows)
    const int wn   = wv & 1;              // 0..1  (N half, 64 cols)

    const int tiles_n = N >> 7;                    // 4 (power of 2)
    const int ln_tn   = __ffs(tiles_n) - 1;
    const int per_m   = (M >> 8) >> 3;             // 256-row tiles per XCD

    const int xcd = blockIdx.x & 7;
    const int j   = blockIdx.x >> 3;
    const int tile_m = (xcd * per_m + (j >> ln_tn)) << 8;
    const int tile_n = (j & (tiles_n - 1)) << 7;

    // --- staging constants ---------------------------------------------
    const int srow = 16 * wv + (lane >> 2);                       // 0..127
    const int sig8 = (((lane & 3) ^ ((lane >> 3) & 3)) << 3);     // elem off

    const __bf16* Ag = A  + (size_t)(tile_m + srow) * K + sig8;
    const __bf16* Bg = Bt + (size_t)(tile_n + srow) * K + sig8;
    const size_t rowK128 = (size_t)128 * K;
    const int lbase = wv * 512;            // wave-uniform LDS elem base

    // --- fragment-read constants ---------------------------------------
    const int lr    = lane & 15;
    const int q4    = lane >> 4;           // logical 16B k-slot 0..3
    const int fslot = ((q4 ^ ((lane >> 1) & 3)) << 3);
    const int arow0 = wm * 64 + lr;        // 0..255
    const int brow0 = wn * 64 + lr;        // 0..127

    const unsigned ldsA0 = (unsigned)(size_t)(las_ptr)&As[0][0];
    const unsigned ldsB0 = (unsigned)(size_t)(las_ptr)&Bs[0][0];
    const unsigned asA = ldsA0 + (unsigned)((arow0 * 32 + fslot) << 1);
    const unsigned asB = ldsB0 + (unsigned)((brow0 * 32 + fslot) << 1);

    f32x4 acc[4][4];
    #pragma unroll
    for (int i = 0; i < 4; ++i)
        #pragma unroll
        for (int jj = 0; jj < 4; ++jj)
            acc[i][jj] = (f32x4){0.f, 0.f, 0.f, 0.f};

    const int NKS = K >> 5;                // k-slices of 32 (even, >= 8)

    auto stage = [&](int ks) {
        const int slot = ks & 3;
        const __bf16* ag = Ag + (ks << 5);
        const __bf16* bg = Bg + (ks << 5);
        load_lds16(ag,           &As[slot][lbase]);
        load_lds16(ag + rowK128, &As[slot][4096 + lbase]);
        load_lds16(bg,           &Bs[slot][lbase]);
    };

    bf16x8 afA[4], bqA[4], afB[4], bqB[4];

#define DSR(d, a, o) asm volatile("ds_read_b128 %0, %1 offset:" o \
                                  : "=v"(d) : "v"(a))
#define SB __builtin_amdgcn_sched_barrier(0)
#define MM4(CAF, CBQ, I)                                                      \
    acc[I][0] = __builtin_amdgcn_mfma_f32_16x16x32_bf16(CAF[I], CBQ[0], acc[I][0], 0, 0, 0); \
    acc[I][1] = __builtin_amdgcn_mfma_f32_16x16x32_bf16(CAF[I], CBQ[1], acc[I][1], 0, 0, 0); \
    acc[I][2] = __builtin_amdgcn_mfma_f32_16x16x32_bf16(CAF[I], CBQ[2], acc[I][2], 0, 0, 0); \
    acc[I][3] = __builtin_amdgcn_mfma_f32_16x16x32_bf16(CAF[I], CBQ[3], acc[I][3], 0, 0, 0);

#define G128_READ(KS, NAF, NBQ)                                               \
    {                                                                         \
        const unsigned aA_ = asA + (unsigned)(((KS) & 3) << 14);              \
        const unsigned aB_ = asB + (unsigned)(((KS) & 3) << 13);              \
        DSR(NAF[0], aA_, "0");    DSR(NAF[1], aA_, "1024");                   \
        DSR(NAF[2], aA_, "2048"); DSR(NAF[3], aA_, "3072");                   \
        DSR(NBQ[0], aB_, "0");    DSR(NBQ[1], aB_, "1024");                   \
        DSR(NBQ[2], aB_, "2048"); DSR(NBQ[3], aB_, "3072");                   \
    }

// steady-state phase: requires ks+4 < NKS and NKS-1-ks >= 3
#define G128_PHASE_FULL(KS, CAF, CBQ, NAF, NBQ)                               \
    {                                                                         \
        const int ks_ = (KS);                                                 \
        asm volatile("s_waitcnt vmcnt(6)" ::: "memory");                      \
        __builtin_amdgcn_s_barrier();                                         \
        asm volatile("" ::: "memory");                                        \
        const int slot_ = (ks_ + 4) & 3;                                      \
        const __bf16* ag_ = Ag + ((ks_ + 4) << 5);                            \
        const __bf16* bg_ = Bg + ((ks_ + 4) << 5);                            \
        const unsigned aA_ = asA + (unsigned)(((ks_ + 1) & 3) << 14);         \
        const unsigned aB_ = asB + (unsigned)(((ks_ + 1) & 3) << 13);         \
        __builtin_amdgcn_s_setprio(1);                                        \
        load_lds16(ag_,           &As[slot_][lbase]);                         \
        MM4(CAF, CBQ, 0) SB;                                                  \
        load_lds16(ag_ + rowK128, &As[slot_][4096 + lbase]);                  \
        load_lds16(bg_,           &Bs[slot_][lbase]);                         \
        MM4(CAF, CBQ, 1) SB;                                                  \
        DSR(NAF[0], aA_, "0");    DSR(NAF[1], aA_, "1024");                   \
        DSR(NAF[2], aA_, "2048"); DSR(NAF[3], aA_, "3072");                   \
        MM4(CAF, CBQ, 2) SB;                                                  \
        DSR(NBQ[0], aB_, "0");    DSR(NBQ[1], aB_, "1024");                   \
        DSR(NBQ[2], aB_, "2048"); DSR(NBQ[3], aB_, "3072");                   \
        MM4(CAF, CBQ, 3)                                                      \
        __builtin_amdgcn_s_setprio(0);                                        \
        asm volatile("s_waitcnt lgkmcnt(0)" ::: "memory");                    \
        __builtin_amdgcn_sched_barrier(0);                                    \
    }

// tail phase: guarded stage/read, vmcnt countdown 6/3/0
#define G128_PHASE_TAIL(KS, CAF, CBQ, NAF, NBQ)                               \
    {                                                                         \
        const int ks_ = (KS);                                                 \
        const int r_  = NKS - 1 - ks_;                                        \
        if (r_ >= 3)      asm volatile("s_waitcnt vmcnt(6)" ::: "memory");    \
        else if (r_ == 2) asm volatile("s_waitcnt vmcnt(3)" ::: "memory");    \
        else if (r_ == 1) asm volatile("s_waitcnt vmcnt(0)" ::: "memory");    \
        __builtin_amdgcn_s_barrier();                                         \
        asm volatile("" ::: "memory");                                        \
        if (ks_ + 4 < NKS) stage(ks_ + 4);                                    \
        if (ks_ + 1 < NKS) G128_READ(ks_ + 1, NAF, NBQ)                       \
        __builtin_amdgcn_s_setprio(1);                                        \
        _Pragma("unroll")                                                     \
        for (int i_ = 0; i_ < 4; ++i_)                                        \
            _Pragma("unroll")                                                 \
            for (int j_ = 0; j_ < 4; ++j_)                                    \
                acc[i_][j_] = __builtin_amdgcn_mfma_f32_16x16x32_bf16(        \
                    CAF[i_], CBQ[j_], acc[i_][j_], 0, 0, 0);                  \
        __builtin_amdgcn_s_setprio(0);                                        \
        asm volatile("s_waitcnt lgkmcnt(0)" ::: "memory");                    \
        __builtin_amdgcn_sched_barrier(0);                                    \
    }

    // prologue: slices 0..2 in flight (9 loads), certify slice 0, preload
    stage(0); stage(1); stage(2);
    asm volatile("s_waitcnt vmcnt(6)" ::: "memory");   // stage(0) retired
    __builtin_amdgcn_s_barrier();                      // slice 0 published
    asm volatile("" ::: "memory");
    stage(3);
    G128_READ(0, afA, bqA)
    asm volatile("s_waitcnt lgkmcnt(0)" ::: "memory");
    __builtin_amdgcn_sched_barrier(0);

    int ks = 0;
    for (; ks + 6 < NKS; ks += 2) {
        G128_PHASE_FULL(ks,     afA, bqA, afB, bqB)
        G128_PHASE_FULL(ks + 1, afB, bqB, afA, bqA)
    }
    for (; ks < NKS; ks += 2) {
        G128_PHASE_TAIL(ks,     afA, bqA, afB, bqB)
        G128_PHASE_TAIL(ks + 1, afB, bqB, afA, bqA)
    }

#undef G128_PHASE_FULL
#undef G128_PHASE_TAIL
#undef G128_READ
#undef MM4
#undef SB
#undef DSR

    // epilogue — C/D layout: col = lane&15, row = (lane>>4)*4 + reg
    const int orow0 = tile_m + wm * 64 + (q4 << 2);
    const int ocol0 = tile_n + wn * 64 + lr;
    #pragma unroll
    for (int i = 0; i < 4; ++i) {
        #pragma unroll
        for (int jj = 0; jj < 4; ++jj) {
            const int col = ocol0 + jj * 16;
            const float bv = bias[col];
            #pragma unroll
            for (int r = 0; r < 4; ++r) {
                const int row = orow0 + i * 16 + r;
                float v = acc[i][jj][r] + bv;
                size_t idx = (size_t)row * N + col;
                if (MODE == 0) {
                    ((__bf16*)out)[idx] = (__bf16)v;
                } else {
                    ((float*)out)[idx] = v + (float)resid[idx];
                }
            }
        }
    }
}

// ---------------------------------------------------------------------------
// R13 (best measured): 256x256-tile GEMM2, 512 threads (8 waves, 2Mx4N),
// 4-slot k-slice ring, 2-deep register fragment pipeline, asm ds_read
// fragment loads, fine-grained per-phase interleave. vmcnt(8)/4/0.
// ---------------------------------------------------------------------------
template<int MODE>
__global__ __launch_bounds__(512, 1)
void gemm256_kernel(const __bf16* __restrict__ A, const __bf16* __restrict__ Bt,
                    const float* __restrict__ bias, void* __restrict__ out,
                    int M, int N, int K)
{
    __shared__ __bf16 As[4][256 * 32];
    __shared__ __bf16 Bs[4][256 * 32];

    const int tid  = threadIdx.x;
    const int wv   = tid >> 6;            // 0..7
    const int lane = tid & 63;
    const int wm   = wv >> 2;             // 0..1  (M half)
    const int wn   = wv & 3;              // 0..3  (N quarter)

    const int tiles_n = N >> 8;                    // 4 (power of 2)
    const int ln_tn   = __ffs(tiles_n) - 1;
    const int per_m   = (M >> 8) >> 3;             // 256-row tiles per XCD

    const int xcd = blockIdx.x & 7;
    const int j   = blockIdx.x >> 3;
    const int tile_m = (xcd * per_m + (j >> ln_tn)) << 8;
    const int tile_n = (j & (tiles_n - 1)) << 8;

    // --- staging constants ---------------------------------------------
    const int srow = 16 * wv + (lane >> 2);                       // 0..127
    const int sig8 = (((lane & 3) ^ ((lane >> 3) & 3)) << 3);     // elem off

    const __bf16* Ag = A  + (size_t)(tile_m + srow) * K + sig8;
    const __bf16* Bg = Bt + (size_t)(tile_n + srow) * K + sig8;
    const size_t rowK128 = (size_t)128 * K;
    const int lbase = wv * 512;            // wave-uniform LDS elem base

    // --- fragment-read constants ---------------------------------------
    const int lr    = lane & 15;           // row within 16-row fragment
    const int q4    = lane >> 4;           // logical 16B k-slot 0..3
    const int fslot = ((q4 ^ ((lane >> 1) & 3)) << 3);   // swizzled elem off
    const int arow0 = wm * 128 + lr;
    const int brow0 = wn * 64 + lr;

    // raw 32-bit LDS byte addresses of slot-0 fragments
    const unsigned ldsA0 = (unsigned)(size_t)(las_ptr)&As[0][0];
    const unsigned ldsB0 = (unsigned)(size_t)(las_ptr)&Bs[0][0];
    const unsigned asA = ldsA0 + (unsigned)((arow0 * 32 + fslot) << 1);
    const unsigned asB = ldsB0 + (unsigned)((brow0 * 32 + fslot) << 1);

    f32x4 acc[8][4];
    #pragma unroll
    for (int i = 0; i < 8; ++i)
        #pragma unroll
        for (int jj = 0; jj < 4; ++jj)
            acc[i][jj] = (f32x4){0.f, 0.f, 0.f, 0.f};

    const int NKS = K >> 5;                // k-slices of 32 (even, >= 8)

    auto stage = [&](int ks) {
        const int slot = ks & 3;
        const __bf16* ag = Ag + (ks << 5);
        const __bf16* bg = Bg + (ks << 5);
        load_lds16(ag,           &As[slot][lbase]);
        load_lds16(ag + rowK128, &As[slot][4096 + lbase]);
        load_lds16(bg,           &Bs[slot][lbase]);
        load_lds16(bg + rowK128, &Bs[slot][4096 + lbase]);
    };

    bf16x8 afA[8], bqA[4], afB[8], bqB[4];

#define DSR(d, a, o) asm volatile("ds_read_b128 %0, %1 offset:" o \
                                  : "=v"(d) : "v"(a))
#define SB __builtin_amdgcn_sched_barrier(0)
#define MM4(CAF, CBQ, I)                                                      \
    acc[I][0] = __builtin_amdgcn_mfma_f32_16x16x32_bf16(CAF[I], CBQ[0], acc[I][0], 0, 0, 0); \
    acc[I][1] = __builtin_amdgcn_mfma_f32_16x16x32_bf16(CAF[I], CBQ[1], acc[I][1], 0, 0, 0); \
    acc[I][2] = __builtin_amdgcn_mfma_f32_16x16x32_bf16(CAF[I], CBQ[2], acc[I][2], 0, 0, 0); \
    acc[I][3] = __builtin_amdgcn_mfma_f32_16x16x32_bf16(CAF[I], CBQ[3], acc[I][3], 0, 0, 0);

#define G256_READ(KS, NAF, NBQ)                                               \
    {                                                                         \
        const unsigned aA_ = asA + (unsigned)(((KS) & 3) << 14);              \
        const unsigned aB_ = asB + (unsigned)(((KS) & 3) << 14);              \
        DSR(NAF[0], aA_, "0");    DSR(NAF[1], aA_, "1024");                   \
        DSR(NAF[2], aA_, "2048"); DSR(NAF[3], aA_, "3072");                   \
        DSR(NAF[4], aA_, "4096"); DSR(NAF[5], aA_, "5120");                   \
        DSR(NAF[6], aA_, "6144"); DSR(NAF[7], aA_, "7168");                   \
        DSR(NBQ[0], aB_, "0");    DSR(NBQ[1], aB_, "1024");                   \
        DSR(NBQ[2], aB_, "2048"); DSR(NBQ[3], aB_, "3072");                   \
    }

// steady-state phase: requires ks+4 < NKS (stage valid) and NKS-1-ks >= 3
#define G256_PHASE_FULL(KS, CAF, CBQ, NAF, NBQ)                               \
    {                                                                         \
        const int ks_ = (KS);                                                 \
        asm volatile("s_waitcnt vmcnt(8)" ::: "memory");                      \
        __builtin_amdgcn_s_barrier();                                         \
        asm volatile("" ::: "memory");                                        \
        const int slot_ = (ks_ + 4) & 3;                                      \
        const __bf16* ag_ = Ag + ((ks_ + 4) << 5);                            \
        const __bf16* bg_ = Bg + ((ks_ + 4) << 5);                            \
        const unsigned aA_ = asA + (unsigned)(((ks_ + 1) & 3) << 14);         \
        const unsigned aB_ = asB + (unsigned)(((ks_ + 1) & 3) << 14);         \
        __builtin_amdgcn_s_setprio(1);                                        \
        load_lds16(ag_,           &As[slot_][lbase]);                         \
        MM4(CAF, CBQ, 0) SB;                                                  \
        load_lds16(ag_ + rowK128, &As[slot_][4096 + lbase]);                  \
        MM4(CAF, CBQ, 1) SB;                                                  \
        load_lds16(bg_,           &Bs[slot_][lbase]);                         \
        MM4(CAF, CBQ, 2) SB;                                                  \
        load_lds16(bg_ + rowK128, &Bs[slot_][4096 + lbase]);                  \
        MM4(CAF, CBQ, 3) SB;                                                  \
        DSR(NAF[0], aA_, "0"); DSR(NAF[1], aA_, "1024");                      \
        DSR(NAF[2], aA_, "2048");                                             \
        MM4(CAF, CBQ, 4) SB;                                                  \
        DSR(NAF[3], aA_, "3072"); DSR(NAF[4], aA_, "4096");                   \
        DSR(NAF[5], aA_, "5120");                                             \
        MM4(CAF, CBQ, 5) SB;                                                  \
        DSR(NAF[6], aA_, "6144"); DSR(NAF[7], aA_, "7168");                   \
        DSR(NBQ[0], aB_, "0");                                                \
        MM4(CAF, CBQ, 6) SB;                                                  \
        DSR(NBQ[1], aB_, "1024"); DSR(NBQ[2], aB_, "2048");                   \
        DSR(NBQ[3], aB_, "3072");                                             \
        MM4(CAF, CBQ, 7)                                                      \
        __builtin_amdgcn_s_setprio(0);                                        \
        asm volatile("s_waitcnt lgkmcnt(0)" ::: "memory");                    \
        __builtin_amdgcn_sched_barrier(0);                                    \
    }

// tail phase: guarded stages/reads, vmcnt countdown 8/4/0
#define G256_PHASE_TAIL(KS, CAF, CBQ, NAF, NBQ)                               \
    {                                                                         \
        const int ks_ = (KS);                                                 \
        const int r_  = NKS - 1 - ks_;                                        \
        if (r_ >= 3)      asm volatile("s_waitcnt vmcnt(8)" ::: "memory");    \
        else if (r_ == 2) asm volatile("s_waitcnt vmcnt(4)" ::: "memory");    \
        else if (r_ == 1) asm volatile("s_waitcnt vmcnt(0)" ::: "memory");    \
        __builtin_amdgcn_s_barrier();                                         \
        asm volatile("" ::: "memory");                                        \
        if (ks_ + 4 < NKS) stage(ks_ + 4);                                    \
        if (ks_ + 1 < NKS) G256_READ(ks_ + 1, NAF, NBQ)                       \
        __builtin_amdgcn_s_setprio(1);                                        \
        _Pragma("unroll")                                                     \
        for (int i_ = 0; i_ < 8; ++i_)                                        \
            _Pragma("unroll")                                                 \
            for (int j_ = 0; j_ < 4; ++j_)                                    \
                acc[i_][j_] = __builtin_amdgcn_mfma_f32_16x16x32_bf16(        \
                    CAF[i_], CBQ[j_], acc[i_][j_], 0, 0, 0);                  \
        __builtin_amdgcn_s_setprio(0);                                        \
        asm volatile("s_waitcnt lgkmcnt(0)" ::: "memory");                    \
        __builtin_amdgcn_sched_barrier(0);                                    \
    }

    // prologue: slices 0..2 in flight, then certify slice 0 and preload its
    // fragments into set A (the ks=0 phase's "current" set).
    stage(0); stage(1); stage(2);
    asm volatile("s_waitcnt vmcnt(8)" ::: "memory");   // stage(0) retired
    __builtin_amdgcn_s_barrier();                      // slice 0 published
    asm volatile("" ::: "memory");
    stage(3);                                          // slot 3 (no conflict)
    G256_READ(0, afA, bqA)
    asm volatile("s_waitcnt lgkmcnt(0)" ::: "memory"); // drained before ks=0 barrier
    __builtin_amdgcn_sched_barrier(0);

    int ks = 0;
    for (; ks + 6 < NKS; ks += 2) {
        G256_PHASE_FULL(ks,     afA, bqA, afB, bqB)
        G256_PHASE_FULL(ks + 1, afB, bqB, afA, bqA)
    }
    for (; ks < NKS; ks += 2) {
        G256_PHASE_TAIL(ks,     afA, bqA, afB, bqB)
        G256_PHASE_TAIL(ks + 1, afB, bqB, afA, bqA)
    }

#undef G256_PHASE_FULL
#undef G256_PHASE_TAIL
#undef G256_READ
#undef MM4
#undef SB
#undef DSR

    // epilogue — C/D layout: col = lane&15, row = (lane>>4)*4 + reg
    const int orow0 = tile_m + wm * 128 + (q4 << 2);
    const int ocol0 = tile_n + wn * 64 + lr;
    #pragma unroll
    for (int i = 0; i < 8; ++i) {
        #pragma unroll
        for (int jj = 0; jj < 4; ++jj) {
            const int col = ocol0 + jj * 16;
            const float bv = bias[col];
            #pragma unroll
            for (int r = 0; r < 4; ++r) {
                const int row = orow0 + i * 16 + r;
                float v = acc[i][jj][r] + bv;
                if (MODE == 1) {
                    float g = 0.5f * v * (1.0f + erff(v * 0.70710678118654752f));
                    ((__bf16*)out)[(size_t)row * N + col] = (__bf16)g;
                } else {
                    ((__bf16*)out)[(size_t)row * N + col] = (__bf16)v;
                }
            }
        }
    }
}

// ---------------------------------------------------------------------------
// R18 scan_ln: 256 threads/block (4 waves), 2 consecutive d per lane.
// bf16x2 loads; per token: in-lane adds -> shfl_xor butterfly -> 4-partial
// LDS exchange + barrier. 65K threads machine-wide (DVFS-safe; R17's 16K
// standalone triggered a ~2x clock-drop poisoning of downstream kernels).
// ---------------------------------------------------------------------------
__global__ __launch_bounds__(256)
void scan_ln_kernel(const __bf16* __restrict__ xb, const __bf16* __restrict__ omega,
                    const float* __restrict__ log_scale,
                    const float* __restrict__ gamma, const float* __restrict__ beta,
                    __bf16* __restrict__ ctx)
{
    const int chunk = blockIdx.x;        // 0..255  (b*64 + n)
    const int tid   = threadIdx.x;       // 0..255
    const int lane  = tid & 63, wv = tid >> 6;   // 4 waves
    const int d0    = tid << 1;          // 2 consecutive d per lane
    const size_t base = (size_t)chunk * 64 * 512;

    float scale[2], g0[2], g1[2], g2[2], g3[2], e0[2], e1[2], e2[2], e3[2];
    #pragma unroll
    for (int u = 0; u < 2; ++u) {
        const int d = d0 + u;
        scale[u] = expf(log_scale[d]);
        g0[u] = gamma[d]; g1[u] = gamma[512 + d]; g2[u] = gamma[1024 + d]; g3[u] = gamma[1536 + d];
        e0[u] = beta[d];  e1[u] = beta[512 + d];  e2[u] = beta[1024 + d];  e3[u] = beta[1536 + d];
    }

    float phi[2] = {0.f, 0.f}, scr[2] = {0.f, 0.f}, sci[2] = {0.f, 0.f};
    __shared__ float red[2][8];          // [slot][4 sums | 4 sumsq]

    bf16x2 om_n = *(const bf16x2*)&omega[base + d0];
    bf16x2 xv_n = *(const bf16x2*)&xb[base + d0];

    for (int c = 0; c < 64; ++c) {
        const bf16x2 omv = om_n;
        const bf16x2 xvv = xv_n;
        if (c < 63) {
            om_n = *(const bf16x2*)&omega[base + (size_t)(c + 1) * 512 + d0];
            xv_n = *(const bf16x2*)&xb[base + (size_t)(c + 1) * 512 + d0];
        }
        const float rsq = rsqrtf((float)(c + 1));
        const float inv = 1.0f / (float)(c + 1);

        float cr[2], ci[2], rr[2], ri[2];
        float s = 0.f, s2 = 0.f;
        #pragma unroll
        for (int u = 0; u < 2; ++u) {
            const float om = (float)omv[u];
            const float xv = (float)xvv[u];
            phi[u] += om * scale[u] * rsq;
            float sp, cp;
            __sincosf(phi[u], &sp, &cp);
            cr[u] = xv * cp; ci[u] = xv * sp;
            scr[u] += cr[u]; sci[u] += ci[u];
            const float mr = scr[u] * inv, mi = sci[u] * inv;
            rr[u] = mr * cp + mi * sp;
            ri[u] = mi * cp - mr * sp;
            s  += cr[u] + ci[u] + rr[u] + ri[u];
            s2 += cr[u]*cr[u] + ci[u]*ci[u] + rr[u]*rr[u] + ri[u]*ri[u];
        }
        #pragma unroll
        for (int o = 32; o > 0; o >>= 1) {
            s  += __shfl_xor(s, o);
            s2 += __shfl_xor(s2, o);
        }
        if (lane == 0) { red[c & 1][wv] = s; red[c & 1][4 + wv] = s2; }
        __syncthreads();
        const float S  = red[c & 1][0] + red[c & 1][1] + red[c & 1][2] + red[c & 1][3];
        const float S2 = red[c & 1][4] + red[c & 1][5] + red[c & 1][6] + red[c & 1][7];
        const float mu   = S * (1.0f / 2048.0f);
        const float var  = S2 * (1.0f / 2048.0f) - mu * mu;
        const float rstd = rsqrtf(var + 1e-5f);

        const size_t ob = ((size_t)chunk * 64 + c) * 2048;
        bf16x2 o0, o1, o2, o3;
        #pragma unroll
        for (int u = 0; u < 2; ++u) {
            o0[u] = (__bf16)(((cr[u] - mu) * rstd) * g0[u] + e0[u]);
            o1[u] = (__bf16)(((ci[u] - mu) * rstd) * g1[u] + e1[u]);
            o2[u] = (__bf16)(((rr[u] - mu) * rstd) * g2[u] + e2[u]);
            o3[u] = (__bf16)(((ri[u] - mu) * rstd) * g3[u] + e3[u]);
        }
        *(bf16x2*)&ctx[ob + d0]        = o0;
        *(bf16x2*)&ctx[ob + 512 + d0]  = o1;
        *(bf16x2*)&ctx[ob + 1024 + d0] = o2;
        *(bf16x2*)&ctx[ob + 1536 + d0] = o3;
    }
}

// ---------------------------------------------------------------------------
// Workspace layout (bytes):
//   xb    @ 0          : 16,777,216  (16384x512 bf16)
//   womT  @ 16777216   : 524,288     (512x512 bf16, transposed)
//   w1T   @ 17301504   : 4,194,304   (1024x2048 bf16, transposed)
//   w2T   @ 21495808   : 1,048,576   (512x1024 bf16, transposed)
//   omega @ 22544384   : 16,777,216  (16384x512 bf16) — region reused as h
//   h     @ 22544384   : 33,554,432  (16384x1024 bf16)
//   ctx   @ 56098816   : 67,108,864  (16384x2048 bf16)
// ---------------------------------------------------------------------------
extern "C" void kernel_launch(void* const* d_in, const int* in_sizes, int n_in,
                              void* d_out, int out_size, void* d_ws, size_t ws_size,
                              hipStream_t stream)
{
    const float* x         = (const float*)d_in[0];
    const float* W_omega   = (const float*)d_in[1];
    const float* b_omega   = (const float*)d_in[2];
    const float* log_scale = (const float*)d_in[3];
    const float* ln_gamma  = (const float*)d_in[4];
    const float* ln_beta   = (const float*)d_in[5];
    const float* W1        = (const float*)d_in[6];
    const float* b1        = (const float*)d_in[7];
    const float* W2        = (const float*)d_in[8];
    const float* b2        = (const float*)d_in[9];
    float* out = (float*)d_out;

    char* ws = (char*)d_ws;
    __bf16* xb    = (__bf16*)(ws);
    __bf16* womT  = (__bf16*)(ws + 16777216);
    __bf16* w1T   = (__bf16*)(ws + 17301504);
    __bf16* w2T   = (__bf16*)(ws + 21495808);
    __bf16* omega = (__bf16*)(ws + 22544384);
    __bf16* hbuf  = (__bf16*)(ws + 22544384);   // reuses omega region (safe:
                                                // omega dead after scan)
    __bf16* ctx   = (__bf16*)(ws + 56098816);

    // 1. fused cast + weight transposes (one launch)
    prep_kernel<<<11008, 256, 0, stream>>>(x, xb, W_omega, womT, W1, w1T, W2, w2T);

    // 2. omega = x @ W_omega + b_omega  (bf16 out) — R20 256x128 ring kernel
    gemm128_kernel<0><<<256, 512, 0, stream>>>(xb, womT, b_omega, nullptr, omega, 16384, 512, 512);

    // 3. chunk scan + LayerNorm -> ctx — R18 4-wave, bf16x2, 65K threads
    scan_ln_kernel<<<256, 256, 0, stream>>>(xb, omega, log_scale, ln_gamma, ln_beta, ctx);

    // 4. h = gelu(ctx @ W1 + b1)  (bf16 out) — R13 interleaved ring kernel
    gemm256_kernel<1><<<256, 512, 0, stream>>>(ctx, w1T, b1, hbuf, 16384, 1024, 2048);

    // 5. out = x + h @ W2 + b2  (fp32 out, bf16 resid) — R20 256x128 kernel
    gemm128_kernel<2><<<256, 512, 0, stream>>>(hbuf, w2T, b2, xb, out, 16384, 512, 1024);
}

// Round 12
// 255.860 us; speedup vs baseline: 1.0834x; 1.0114x over previous
//
#include <hip/hip_runtime.h>
#include <hip/hip_bf16.h>
#include <math.h>

// ---------------------------------------------------------------------------
// PSI_47931835024047: x@W_omega -> chunked phase cumsum/rotation -> LN ->
//                     W1+gelu -> W2 + residual.
// B=4 S=4096 D=512 C=64. All GEMMs bf16 MFMA.
// R21: LN FOLDED INTO GEMM2 -> barrier-free scan.
//   LN(raw)@W1 = rstd*(raw@W1gamma) - mu*rstd*u + v  (u=gamma@W1, v=beta@W1)
//   - prep: W1 transpose multiplies by gamma[k]; 32 extra blocks compute
//     u,v (overlapped with the cast -> no DVFS window).
//   - scan_raw: 256x512 (131K threads, R15-proven DVFS-safe), writes RAW
//     cr/ci/rr/ri + per-token (rstd, mu*rstd) via wave-partials in LDS;
//     ONE barrier total (was 64 block-wide barriers = the ~55us cost).
//   - gemm256 epilogue applies the affine fold in fp32, then gelu.
//   gemm128 (R20) and gemm256 GEMM body (R13) unchanged.
// ---------------------------------------------------------------------------

typedef __bf16 bf16x8 __attribute__((ext_vector_type(8)));
typedef __bf16 bf16x4 __attribute__((ext_vector_type(4)));
typedef __bf16 bf16x2 __attribute__((ext_vector_type(2)));
typedef float  f32x4  __attribute__((ext_vector_type(4)));

typedef __attribute__((address_space(1))) void* gas_ptr;
typedef __attribute__((address_space(3))) void* las_ptr;

// wave-uniform LDS base; each lane deposits 16 B at base + lane*16
__device__ __forceinline__ void load_lds16(const void* g, void* l) {
    __builtin_amdgcn_global_load_lds((gas_ptr)g, (las_ptr)l, 16, 0, 0);
}

// ---------------------------------------------------------------------------
// Fused prep: (a) x->bf16 cast, (b) W_omega^T, (c) W1^T * gamma[k],
// (d) W2^T, (e) u = gamma@W1, v = beta@W1. One launch.
// ---------------------------------------------------------------------------
__device__ __forceinline__ void transpose_tile(const float* __restrict__ in,
                                               __bf16* __restrict__ out,
                                               int K, int N, int bx, int by,
                                               float (*tile)[33],
                                               const float* __restrict__ colscale)
{
    const int tid = threadIdx.x;
    const int tx = tid & 31, ty = tid >> 5;       // (32, 8)
    const int n0 = bx * 32, k0 = by * 32;
    #pragma unroll
    for (int i = 0; i < 32; i += 8)
        tile[ty + i][tx] = in[(size_t)(k0 + ty + i) * N + n0 + tx];
    __syncthreads();
    const float cs = colscale ? colscale[k0 + tx] : 1.0f;  // k = k0+tx
    #pragma unroll
    for (int i = 0; i < 32; i += 8)
        out[(size_t)(n0 + ty + i) * K + k0 + tx] = (__bf16)(tile[tx][ty + i] * cs);
}

__global__ __launch_bounds__(256)
void prep_kernel(const float* __restrict__ x, __bf16* __restrict__ xb,
                 const float* __restrict__ W_omega, __bf16* __restrict__ womT,
                 const float* __restrict__ W1, __bf16* __restrict__ w1T,
                 const float* __restrict__ W2, __bf16* __restrict__ w2T,
                 const float* __restrict__ gamma, const float* __restrict__ beta,
                 float* __restrict__ ubuf, float* __restrict__ vbuf)
{
    __shared__ float tile[32][33];
    __shared__ float uv[32][8][2];
    const int bid = blockIdx.x;
    if (bid < 8192) {
        int i = bid * 256 + threadIdx.x;          // 2097152 float4's
        float4 v = ((const float4*)x)[i];
        bf16x4 o = { (__bf16)v.x, (__bf16)v.y, (__bf16)v.z, (__bf16)v.w };
        ((bf16x4*)xb)[i] = o;
    } else if (bid < 8448) {
        int t = bid - 8192;                       // 16 x 16
        transpose_tile(W_omega, womT, 512, 512, t & 15, t >> 4, tile, nullptr);
    } else if (bid < 10496) {
        int t = bid - 8448;                       // 32 x 64
        transpose_tile(W1, w1T, 2048, 1024, t & 31, t >> 5, tile, gamma);
    } else if (bid < 11008) {
        int t = bid - 10496;                      // 16 x 32
        transpose_tile(W2, w2T, 1024, 512, t & 15, t >> 4, tile, nullptr);
    } else {
        // u[n] = sum_k gamma[k]*W1[k,n]; v[n] = sum_k beta[k]*W1[k,n]
        // 32 blocks x 32 n-cols; 8 k-strips of 256 per n.
        const int b  = bid - 11008;               // 0..31
        const int nl = threadIdx.x & 31;          // n within block
        const int st = threadIdx.x >> 5;          // k-strip 0..7
        const int n  = b * 32 + nl;
        float su = 0.f, sv = 0.f;
        const int k0 = st * 256;
        for (int kk = 0; kk < 256; ++kk) {
            const int k = k0 + kk;
            const float w = W1[(size_t)k * 1024 + n];
            su += gamma[k] * w;
            sv += beta[k] * w;
        }
        uv[nl][st][0] = su; uv[nl][st][1] = sv;
        __syncthreads();
        if (threadIdx.x < 32) {
            float U = 0.f, V = 0.f;
            #pragma unroll
            for (int s = 0; s < 8; ++s) { U += uv[threadIdx.x][s][0]; V += uv[threadIdx.x][s][1]; }
            ubuf[b * 32 + threadIdx.x] = U;
            vbuf[b * 32 + threadIdx.x] = V;
        }
    }
}

// ---------------------------------------------------------------------------
// R20: 256x128-tile GEMM (R13 ring) for GEMM1 (MODE 0) and GEMM3 (MODE 2).
// 8 waves 4Mx2N, 64x64/wave; 3 loads/slice (vmcnt 6/3/0); LDS 96 KiB.
// ---------------------------------------------------------------------------
template<int MODE>
__global__ __launch_bounds__(512, 1)
void gemm128_kernel(const __bf16* __restrict__ A, const __bf16* __restrict__ Bt,
                    const float* __restrict__ bias, const __bf16* __restrict__ resid,
                    void* __restrict__ out, int M, int N, int K)
{
    __shared__ __bf16 As[4][256 * 32];
    __shared__ __bf16 Bs[4][128 * 32];

    const int tid  = threadIdx.x;
    const int wv   = tid >> 6;            // 0..7
    const int lane = tid & 63;
    const int wm   = wv >> 1;             // 0..3  (M quarter, 64 rows)
    const int wn   = wv & 1;              // 0..1  (N half, 64 cols)

    const int tiles_n = N >> 7;                    // 4 (power of 2)
    const int ln_tn   = __ffs(tiles_n) - 1;
    const int per_m   = (M >> 8) >> 3;             // 256-row tiles per XCD

    const int xcd = blockIdx.x & 7;
    const int j   = blockIdx.x >> 3;
    const int tile_m = (xcd * per_m + (j >> ln_tn)) << 8;
    const int tile_n = (j & (tiles_n - 1)) << 7;

    const int srow = 16 * wv + (lane >> 2);                       // 0..127
    const int sig8 = (((lane & 3) ^ ((lane >> 3) & 3)) << 3);     // elem off

    const __bf16* Ag = A  + (size_t)(tile_m + srow) * K + sig8;
    const __bf16* Bg = Bt + (size_t)(tile_n + srow) * K + sig8;
    const size_t rowK128 = (size_t)128 * K;
    const int lbase = wv * 512;

    const int lr    = lane & 15;
    const int q4    = lane >> 4;
    const int fslot = ((q4 ^ ((lane >> 1) & 3)) << 3);
    const int arow0 = wm * 64 + lr;        // 0..255
    const int brow0 = wn * 64 + lr;        // 0..127

    const unsigned ldsA0 = (unsigned)(size_t)(las_ptr)&As[0][0];
    const unsigned ldsB0 = (unsigned)(size_t)(las_ptr)&Bs[0][0];
    const unsigned asA = ldsA0 + (unsigned)((arow0 * 32 + fslot) << 1);
    const unsigned asB = ldsB0 + (unsigned)((brow0 * 32 + fslot) << 1);

    f32x4 acc[4][4];
    #pragma unroll
    for (int i = 0; i < 4; ++i)
        #pragma unroll
        for (int jj = 0; jj < 4; ++jj)
            acc[i][jj] = (f32x4){0.f, 0.f, 0.f, 0.f};

    const int NKS = K >> 5;

    auto stage = [&](int ks) {
        const int slot = ks & 3;
        const __bf16* ag = Ag + (ks << 5);
        const __bf16* bg = Bg + (ks << 5);
        load_lds16(ag,           &As[slot][lbase]);
        load_lds16(ag + rowK128, &As[slot][4096 + lbase]);
        load_lds16(bg,           &Bs[slot][lbase]);
    };

    bf16x8 afA[4], bqA[4], afB[4], bqB[4];

#define DSR(d, a, o) asm volatile("ds_read_b128 %0, %1 offset:" o \
                                  : "=v"(d) : "v"(a))
#define SB __builtin_amdgcn_sched_barrier(0)
#define MM4(CAF, CBQ, I)                                                      \
    acc[I][0] = __builtin_amdgcn_mfma_f32_16x16x32_bf16(CAF[I], CBQ[0], acc[I][0], 0, 0, 0); \
    acc[I][1] = __builtin_amdgcn_mfma_f32_16x16x32_bf16(CAF[I], CBQ[1], acc[I][1], 0, 0, 0); \
    acc[I][2] = __builtin_amdgcn_mfma_f32_16x16x32_bf16(CAF[I], CBQ[2], acc[I][2], 0, 0, 0); \
    acc[I][3] = __builtin_amdgcn_mfma_f32_16x16x32_bf16(CAF[I], CBQ[3], acc[I][3], 0, 0, 0);

#define G128_READ(KS, NAF, NBQ)                                               \
    {                                                                         \
        const unsigned aA_ = asA + (unsigned)(((KS) & 3) << 14);              \
        const unsigned aB_ = asB + (unsigned)(((KS) & 3) << 13);              \
        DSR(NAF[0], aA_, "0");    DSR(NAF[1], aA_, "1024");                   \
        DSR(NAF[2], aA_, "2048"); DSR(NAF[3], aA_, "3072");                   \
        DSR(NBQ[0], aB_, "0");    DSR(NBQ[1], aB_, "1024");                   \
        DSR(NBQ[2], aB_, "2048"); DSR(NBQ[3], aB_, "3072");                   \
    }

#define G128_PHASE_FULL(KS, CAF, CBQ, NAF, NBQ)                               \
    {                                                                         \
        const int ks_ = (KS);                                                 \
        asm volatile("s_waitcnt vmcnt(6)" ::: "memory");                      \
        __builtin_amdgcn_s_barrier();                                         \
        asm volatile("" ::: "memory");                                        \
        const int slot_ = (ks_ + 4) & 3;                                      \
        const __bf16* ag_ = Ag + ((ks_ + 4) << 5);                            \
        const __bf16* bg_ = Bg + ((ks_ + 4) << 5);                            \
        const unsigned aA_ = asA + (unsigned)(((ks_ + 1) & 3) << 14);         \
        const unsigned aB_ = asB + (unsigned)(((ks_ + 1) & 3) << 13);         \
        __builtin_amdgcn_s_setprio(1);                                        \
        load_lds16(ag_,           &As[slot_][lbase]);                         \
        MM4(CAF, CBQ, 0) SB;                                                  \
        load_lds16(ag_ + rowK128, &As[slot_][4096 + lbase]);                  \
        load_lds16(bg_,           &Bs[slot_][lbase]);                         \
        MM4(CAF, CBQ, 1) SB;                                                  \
        DSR(NAF[0], aA_, "0");    DSR(NAF[1], aA_, "1024");                   \
        DSR(NAF[2], aA_, "2048"); DSR(NAF[3], aA_, "3072");                   \
        MM4(CAF, CBQ, 2) SB;                                                  \
        DSR(NBQ[0], aB_, "0");    DSR(NBQ[1], aB_, "1024");                   \
        DSR(NBQ[2], aB_, "2048"); DSR(NBQ[3], aB_, "3072");                   \
        MM4(CAF, CBQ, 3)                                                      \
        __builtin_amdgcn_s_setprio(0);                                        \
        asm volatile("s_waitcnt lgkmcnt(0)" ::: "memory");                    \
        __builtin_amdgcn_sched_barrier(0);                                    \
    }

#define G128_PHASE_TAIL(KS, CAF, CBQ, NAF, NBQ)                               \
    {                                                                         \
        const int ks_ = (KS);                                                 \
        const int r_  = NKS - 1 - ks_;                                        \
        if (r_ >= 3)      asm volatile("s_waitcnt vmcnt(6)" ::: "memory");    \
        else if (r_ == 2) asm volatile("s_waitcnt vmcnt(3)" ::: "memory");    \
        else if (r_ == 1) asm volatile("s_waitcnt vmcnt(0)" ::: "memory");    \
        __builtin_amdgcn_s_barrier();                                         \
        asm volatile("" ::: "memory");                                        \
        if (ks_ + 4 < NKS) stage(ks_ + 4);                                    \
        if (ks_ + 1 < NKS) G128_READ(ks_ + 1, NAF, NBQ)                       \
        __builtin_amdgcn_s_setprio(1);                                        \
        _Pragma("unroll")                                                     \
        for (int i_ = 0; i_ < 4; ++i_)                                        \
            _Pragma("unroll")                                                 \
            for (int j_ = 0; j_ < 4; ++j_)                                    \
                acc[i_][j_] = __builtin_amdgcn_mfma_f32_16x16x32_bf16(        \
                    CAF[i_], CBQ[j_], acc[i_][j_], 0, 0, 0);                  \
        __builtin_amdgcn_s_setprio(0);                                        \
        asm volatile("s_waitcnt lgkmcnt(0)" ::: "memory");                    \
        __builtin_amdgcn_sched_barrier(0);                                    \
    }

    stage(0); stage(1); stage(2);
    asm volatile("s_waitcnt vmcnt(6)" ::: "memory");
    __builtin_amdgcn_s_barrier();
    asm volatile("" ::: "memory");
    stage(3);
    G128_READ(0, afA, bqA)
    asm volatile("s_waitcnt lgkmcnt(0)" ::: "memory");
    __builtin_amdgcn_sched_barrier(0);

    int ks = 0;
    for (; ks + 6 < NKS; ks += 2) {
        G128_PHASE_FULL(ks,     afA, bqA, afB, bqB)
        G128_PHASE_FULL(ks + 1, afB, bqB, afA, bqA)
    }
    for (; ks < NKS; ks += 2) {
        G128_PHASE_TAIL(ks,     afA, bqA, afB, bqB)
        G128_PHASE_TAIL(ks + 1, afB, bqB, afA, bqA)
    }

#undef G128_PHASE_FULL
#undef G128_PHASE_TAIL
#undef G128_READ
#undef MM4
#undef SB
#undef DSR

    const int orow0 = tile_m + wm * 64 + (q4 << 2);
    const int ocol0 = tile_n + wn * 64 + lr;
    #pragma unroll
    for (int i = 0; i < 4; ++i) {
        #pragma unroll
        for (int jj = 0; jj < 4; ++jj) {
            const int col = ocol0 + jj * 16;
            const float bv = bias[col];
            #pragma unroll
            for (int r = 0; r < 4; ++r) {
                const int row = orow0 + i * 16 + r;
                float v = acc[i][jj][r] + bv;
                size_t idx = (size_t)row * N + col;
                if (MODE == 0) {
                    ((__bf16*)out)[idx] = (__bf16)v;
                } else {
                    ((float*)out)[idx] = v + (float)resid[idx];
                }
            }
        }
    }
}

// ---------------------------------------------------------------------------
// R13 GEMM body + R21 LN-folded gelu epilogue (GEMM2 only).
// z[r,n] = rstd_r*acc - (mu_r*rstd_r)*u[n] + v[n] + b1[n]; out = gelu(z).
// musig[r] = {rstd, mu*rstd} (fp32, from scan_raw).
// ---------------------------------------------------------------------------
__global__ __launch_bounds__(512, 1)
void gemm256_kernel(const __bf16* __restrict__ A, const __bf16* __restrict__ Bt,
                    const float* __restrict__ bias, const float* __restrict__ ubuf,
                    const float* __restrict__ vbuf, const float2* __restrict__ musig,
                    __bf16* __restrict__ out, int M, int N, int K)
{
    __shared__ __bf16 As[4][256 * 32];
    __shared__ __bf16 Bs[4][256 * 32];

    const int tid  = threadIdx.x;
    const int wv   = tid >> 6;            // 0..7
    const int lane = tid & 63;
    const int wm   = wv >> 2;             // 0..1  (M half)
    const int wn   = wv & 3;              // 0..3  (N quarter)

    const int tiles_n = N >> 8;                    // 4 (power of 2)
    const int ln_tn   = __ffs(tiles_n) - 1;
    const int per_m   = (M >> 8) >> 3;             // 256-row tiles per XCD

    const int xcd = blockIdx.x & 7;
    const int j   = blockIdx.x >> 3;
    const int tile_m = (xcd * per_m + (j >> ln_tn)) << 8;
    const int tile_n = (j & (tiles_n - 1)) << 8;

    const int srow = 16 * wv + (lane >> 2);                       // 0..127
    const int sig8 = (((lane & 3) ^ ((lane >> 3) & 3)) << 3);     // elem off

    const __bf16* Ag = A  + (size_t)(tile_m + srow) * K + sig8;
    const __bf16* Bg = Bt + (size_t)(tile_n + srow) * K + sig8;
    const size_t rowK128 = (size_t)128 * K;
    const int lbase = wv * 512;

    const int lr    = lane & 15;
    const int q4    = lane >> 4;
    const int fslot = ((q4 ^ ((lane >> 1) & 3)) << 3);
    const int arow0 = wm * 128 + lr;
    const int brow0 = wn * 64 + lr;

    const unsigned ldsA0 = (unsigned)(size_t)(las_ptr)&As[0][0];
    const unsigned ldsB0 = (unsigned)(size_t)(las_ptr)&Bs[0][0];
    const unsigned asA = ldsA0 + (unsigned)((arow0 * 32 + fslot) << 1);
    const unsigned asB = ldsB0 + (unsigned)((brow0 * 32 + fslot) << 1);

    f32x4 acc[8][4];
    #pragma unroll
    for (int i = 0; i < 8; ++i)
        #pragma unroll
        for (int jj = 0; jj < 4; ++jj)
            acc[i][jj] = (f32x4){0.f, 0.f, 0.f, 0.f};

    const int NKS = K >> 5;

    auto stage = [&](int ks) {
        const int slot = ks & 3;
        const __bf16* ag = Ag + (ks << 5);
        const __bf16* bg = Bg + (ks << 5);
        load_lds16(ag,           &As[slot][lbase]);
        load_lds16(ag + rowK128, &As[slot][4096 + lbase]);
        load_lds16(bg,           &Bs[slot][lbase]);
        load_lds16(bg + rowK128, &Bs[slot][4096 + lbase]);
    };

    bf16x8 afA[8], bqA[4], afB[8], bqB[4];

#define DSR(d, a, o) asm volatile("ds_read_b128 %0, %1 offset:" o \
                                  : "=v"(d) : "v"(a))
#define SB __builtin_amdgcn_sched_barrier(0)
#define MM4(CAF, CBQ, I)                                                      \
    acc[I][0] = __builtin_amdgcn_mfma_f32_16x16x32_bf16(CAF[I], CBQ[0], acc[I][0], 0, 0, 0); \
    acc[I][1] = __builtin_amdgcn_mfma_f32_16x16x32_bf16(CAF[I], CBQ[1], acc[I][1], 0, 0, 0); \
    acc[I][2] = __builtin_amdgcn_mfma_f32_16x16x32_bf16(CAF[I], CBQ[2], acc[I][2], 0, 0, 0); \
    acc[I][3] = __builtin_amdgcn_mfma_f32_16x16x32_bf16(CAF[I], CBQ[3], acc[I][3], 0, 0, 0);

#define G256_READ(KS, NAF, NBQ)                                               \
    {                                                                         \
        const unsigned aA_ = asA + (unsigned)(((KS) & 3) << 14);              \
        const unsigned aB_ = asB + (unsigned)(((KS) & 3) << 14);              \
        DSR(NAF[0], aA_, "0");    DSR(NAF[1], aA_, "1024");                   \
        DSR(NAF[2], aA_, "2048"); DSR(NAF[3], aA_, "3072");                   \
        DSR(NAF[4], aA_, "4096"); DSR(NAF[5], aA_, "5120");                   \
        DSR(NAF[6], aA_, "6144"); DSR(NAF[7], aA_, "7168");                   \
        DSR(NBQ[0], aB_, "0");    DSR(NBQ[1], aB_, "1024");                   \
        DSR(NBQ[2], aB_, "2048"); DSR(NBQ[3], aB_, "3072");                   \
    }

#define G256_PHASE_FULL(KS, CAF, CBQ, NAF, NBQ)                               \
    {                                                                         \
        const int ks_ = (KS);                                                 \
        asm volatile("s_waitcnt vmcnt(8)" ::: "memory");                      \
        __builtin_amdgcn_s_barrier();                                         \
        asm volatile("" ::: "memory");                                        \
        const int slot_ = (ks_ + 4) & 3;                                      \
        const __bf16* ag_ = Ag + ((ks_ + 4) << 5);                            \
        const __bf16* bg_ = Bg + ((ks_ + 4) << 5);                            \
        const unsigned aA_ = asA + (unsigned)(((ks_ + 1) & 3) << 14);         \
        const unsigned aB_ = asB + (unsigned)(((ks_ + 1) & 3) << 14);         \
        __builtin_amdgcn_s_setprio(1);                                        \
        load_lds16(ag_,           &As[slot_][lbase]);                         \
        MM4(CAF, CBQ, 0) SB;                                                  \
        load_lds16(ag_ + rowK128, &As[slot_][4096 + lbase]);                  \
        MM4(CAF, CBQ, 1) SB;                                                  \
        load_lds16(bg_,           &Bs[slot_][lbase]);                         \
        MM4(CAF, CBQ, 2) SB;                                                  \
        load_lds16(bg_ + rowK128, &Bs[slot_][4096 + lbase]);                  \
        MM4(CAF, CBQ, 3) SB;                                                  \
        DSR(NAF[0], aA_, "0"); DSR(NAF[1], aA_, "1024");                      \
        DSR(NAF[2], aA_, "2048");                                             \
        MM4(CAF, CBQ, 4) SB;                                                  \
        DSR(NAF[3], aA_, "3072"); DSR(NAF[4], aA_, "4096");                   \
        DSR(NAF[5], aA_, "5120");                                             \
        MM4(CAF, CBQ, 5) SB;                                                  \
        DSR(NAF[6], aA_, "6144"); DSR(NAF[7], aA_, "7168");                   \
        DSR(NBQ[0], aB_, "0");                                                \
        MM4(CAF, CBQ, 6) SB;                                                  \
        DSR(NBQ[1], aB_, "1024"); DSR(NBQ[2], aB_, "2048");                   \
        DSR(NBQ[3], aB_, "3072");                                             \
        MM4(CAF, CBQ, 7)                                                      \
        __builtin_amdgcn_s_setprio(0);                                        \
        asm volatile("s_waitcnt lgkmcnt(0)" ::: "memory");                    \
        __builtin_amdgcn_sched_barrier(0);                                    \
    }

#define G256_PHASE_TAIL(KS, CAF, CBQ, NAF, NBQ)                               \
    {                                                                         \
        const int ks_ = (KS);                                                 \
        const int r_  = NKS - 1 - ks_;                                        \
        if (r_ >= 3)      asm volatile("s_waitcnt vmcnt(8)" ::: "memory");    \
        else if (r_ == 2) asm volatile("s_waitcnt vmcnt(4)" ::: "memory");    \
        else if (r_ == 1) asm volatile("s_waitcnt vmcnt(0)" ::: "memory");    \
        __builtin_amdgcn_s_barrier();                                         \
        asm volatile("" ::: "memory");                                        \
        if (ks_ + 4 < NKS) stage(ks_ + 4);                                    \
        if (ks_ + 1 < NKS) G256_READ(ks_ + 1, NAF, NBQ)                       \
        __builtin_amdgcn_s_setprio(1);                                        \
        _Pragma("unroll")                                                     \
        for (int i_ = 0; i_ < 8; ++i_)                                        \
            _Pragma("unroll")                                                 \
            for (int j_ = 0; j_ < 4; ++j_)                                    \
                acc[i_][j_] = __builtin_amdgcn_mfma_f32_16x16x32_bf16(        \
                    CAF[i_], CBQ[j_], acc[i_][j_], 0, 0, 0);                  \
        __builtin_amdgcn_s_setprio(0);                                        \
        asm volatile("s_waitcnt lgkmcnt(0)" ::: "memory");                    \
        __builtin_amdgcn_sched_barrier(0);                                    \
    }

    stage(0); stage(1); stage(2);
    asm volatile("s_waitcnt vmcnt(8)" ::: "memory");
    __builtin_amdgcn_s_barrier();
    asm volatile("" ::: "memory");
    stage(3);
    G256_READ(0, afA, bqA)
    asm volatile("s_waitcnt lgkmcnt(0)" ::: "memory");
    __builtin_amdgcn_sched_barrier(0);

    int ks = 0;
    for (; ks + 6 < NKS; ks += 2) {
        G256_PHASE_FULL(ks,     afA, bqA, afB, bqB)
        G256_PHASE_FULL(ks + 1, afB, bqB, afA, bqA)
    }
    for (; ks < NKS; ks += 2) {
        G256_PHASE_TAIL(ks,     afA, bqA, afB, bqB)
        G256_PHASE_TAIL(ks + 1, afB, bqB, afA, bqA)
    }

#undef G256_PHASE_FULL
#undef G256_PHASE_TAIL
#undef G256_READ
#undef MM4
#undef SB
#undef DSR

    // epilogue — LN fold + gelu. C/D: col = lane&15, row = (lane>>4)*4 + reg
    const int orow0 = tile_m + wm * 128 + (q4 << 2);
    const int ocol0 = tile_n + wn * 64 + lr;
    #pragma unroll
    for (int i = 0; i < 8; ++i) {
        float2 ms[4];
        #pragma unroll
        for (int r = 0; r < 4; ++r)
            ms[r] = musig[orow0 + i * 16 + r];
        #pragma unroll
        for (int jj = 0; jj < 4; ++jj) {
            const int col = ocol0 + jj * 16;
            const float u_c  = ubuf[col];
            const float vb_c = vbuf[col] + bias[col];
            #pragma unroll
            for (int r = 0; r < 4; ++r) {
                const int row = orow0 + i * 16 + r;
                const float z = ms[r].x * acc[i][jj][r] - ms[r].y * u_c + vb_c;
                const float g = 0.5f * z * (1.0f + erff(z * 0.70710678118654752f));
                out[(size_t)row * N + col] = (__bf16)g;
            }
        }
    }
}

// ---------------------------------------------------------------------------
// R21 scan_raw: 256 blocks x 512 threads (131K threads, R15-proven DVFS-safe
// shape). Thread = one (chunk, d) chain; loads/stores scalar bf16 (wave =
// 128 B contiguous, coalesced). Writes RAW cr/ci/rr/ri (bf16) -- LN is
// applied in gemm256's epilogue. Per token: wave-reduce (12 shfl, no
// barrier); lane0 writes wave partial to LDS. ONE barrier at the end; then
// threads 0..63 sum 8 partials/token -> musig[r] = {rstd, mu*rstd} (fp32).
// Partial-sum structure (8 wave-partials per token, summed in order)
// identical to R15/R18 -> same fp32 rounding class.
// ---------------------------------------------------------------------------
__global__ __launch_bounds__(512)
void scan_raw_kernel(const __bf16* __restrict__ xb, const __bf16* __restrict__ omega,
                     const float* __restrict__ log_scale,
                     __bf16* __restrict__ ctx, float2* __restrict__ musig)
{
    const int chunk = blockIdx.x;        // 0..255
    const int d     = threadIdx.x;       // 0..511
    const int lane  = d & 63, wv = d >> 6;
    const size_t base = (size_t)chunk * 64 * 512;

    const float scale = expf(log_scale[d]);
    float phi = 0.f, scr = 0.f, sci = 0.f;

    __shared__ float2 psum[64][8];       // [token][wave] {s, s2} -- 4 KiB

    float om_n = (float)omega[base + d];
    float xv_n = (float)xb[base + d];

    for (int c = 0; c < 64; ++c) {
        const float om = om_n;
        const float xv = xv_n;
        if (c < 63) {
            om_n = (float)omega[base + (size_t)(c + 1) * 512 + d];
            xv_n = (float)xb[base + (size_t)(c + 1) * 512 + d];
        }
        phi += om * scale * rsqrtf((float)(c + 1));
        float sp, cp;
        __sincosf(phi, &sp, &cp);
        const float cr = xv * cp, ci = xv * sp;
        scr += cr; sci += ci;
        const float inv = 1.0f / (float)(c + 1);
        const float mr = scr * inv, mi = sci * inv;
        const float rr = mr * cp + mi * sp;
        const float ri = mi * cp - mr * sp;

        const size_t ob = ((size_t)chunk * 64 + c) * 2048;
        ctx[ob + d]        = (__bf16)cr;
        ctx[ob + 512 + d]  = (__bf16)ci;
        ctx[ob + 1024 + d] = (__bf16)rr;
        ctx[ob + 1536 + d] = (__bf16)ri;

        float s  = cr + ci + rr + ri;
        float s2 = cr * cr + ci * ci + rr * rr + ri * ri;
        #pragma unroll
        for (int o = 32; o > 0; o >>= 1) {
            s  += __shfl_xor(s, o);
            s2 += __shfl_xor(s2, o);
        }
        if (lane == 0) psum[c][wv] = make_float2(s, s2);
    }
    __syncthreads();
    if (d < 64) {
        float S = 0.f, S2 = 0.f;
        #pragma unroll
        for (int w = 0; w < 8; ++w) { S += psum[d][w].x; S2 += psum[d][w].y; }
        const float mu   = S * (1.0f / 2048.0f);
        const float var  = S2 * (1.0f / 2048.0f) - mu * mu;
        const float rstd = rsqrtf(var + 1e-5f);
        musig[chunk * 64 + d] = make_float2(rstd, mu * rstd);
    }
}

// ---------------------------------------------------------------------------
// Workspace layout (bytes):
//   xb    @ 0          : 16,777,216   (16384x512 bf16)
//   womT  @ 16777216   : 524,288
//   w1T   @ 17301504   : 4,194,304    (gamma-folded W1^T)
//   w2T   @ 21495808   : 1,048,576
//   omega @ 22544384   : 16,777,216   — region reused as h
//   h     @ 22544384   : 33,554,432
//   ctx   @ 56098816   : 67,108,864   (RAW cr/ci/rr/ri, bf16)
//   musig @ 123207680  : 131,072      (16384 x float2 {rstd, mu*rstd})
//   ubuf  @ 123338752  : 4,096        (gamma @ W1)
//   vbuf  @ 123342848  : 4,096        (beta @ W1)
// ---------------------------------------------------------------------------
extern "C" void kernel_launch(void* const* d_in, const int* in_sizes, int n_in,
                              void* d_out, int out_size, void* d_ws, size_t ws_size,
                              hipStream_t stream)
{
    const float* x         = (const float*)d_in[0];
    const float* W_omega   = (const float*)d_in[1];
    const float* b_omega   = (const float*)d_in[2];
    const float* log_scale = (const float*)d_in[3];
    const float* ln_gamma  = (const float*)d_in[4];
    const float* ln_beta   = (const float*)d_in[5];
    const float* W1        = (const float*)d_in[6];
    const float* b1        = (const float*)d_in[7];
    const float* W2        = (const float*)d_in[8];
    const float* b2        = (const float*)d_in[9];
    float* out = (float*)d_out;

    char* ws = (char*)d_ws;
    __bf16* xb    = (__bf16*)(ws);
    __bf16* womT  = (__bf16*)(ws + 16777216);
    __bf16* w1T   = (__bf16*)(ws + 17301504);
    __bf16* w2T   = (__bf16*)(ws + 21495808);
    __bf16* omega = (__bf16*)(ws + 22544384);
    __bf16* hbuf  = (__bf16*)(ws + 22544384);   // reuses omega (dead after scan)
    __bf16* ctx   = (__bf16*)(ws + 56098816);
    float2* musig = (float2*)(ws + 123207680);
    float*  ubuf  = (float*)(ws + 123338752);
    float*  vbuf  = (float*)(ws + 123342848);

    // 1. fused cast + weight transposes (gamma-folded W1) + u/v
    prep_kernel<<<11040, 256, 0, stream>>>(x, xb, W_omega, womT, W1, w1T, W2, w2T,
                                           ln_gamma, ln_beta, ubuf, vbuf);

    // 2. omega = x @ W_omega + b_omega  (bf16 out) — 256x128 ring kernel
    gemm128_kernel<0><<<256, 512, 0, stream>>>(xb, womT, b_omega, nullptr, omega, 16384, 512, 512);

    // 3. barrier-free raw scan -> ctx (raw) + musig
    scan_raw_kernel<<<256, 512, 0, stream>>>(xb, omega, log_scale, ctx, musig);

    // 4. h = gelu(LN-fold epilogue(ctx_raw @ w1T')) — R13 ring + folded epilogue
    gemm256_kernel<<<256, 512, 0, stream>>>(ctx, w1T, b1, ubuf, vbuf, musig,
                                            hbuf, 16384, 1024, 2048);

    // 5. out = x + h @ W2 + b2  (fp32 out, bf16 resid) — 256x128 kernel
    gemm128_kernel<2><<<256, 512, 0, stream>>>(hbuf, w2T, b2, xb, out, 16384, 512, 1024);
}